// Round 1
// baseline (71.306 us; speedup 1.0000x reference)
//
#include <hip/hip_runtime.h>
#include <stdint.h>

#define TT 256
#define BB 2048
#define AA 18
#define NTB (TT * BB)

// ws layout:
//   [0..31]  4 doubles: acc[0]=S_ent, acc[1]=S_pol, acc[2]=S_val, acc[3]=spare
//   [32..35] int flag: 1 = done is 1-byte elements, 0 = 4-byte elements
//   [64..)   float c_arr[NTB], l_arr[NTB]   (needs 64 + 8*NTB = ~4.2 MB)

__global__ __launch_bounds__(256) void init_k(const int* __restrict__ done_w,
                                              double* __restrict__ acc,
                                              int* __restrict__ flag) {
    int tid = threadIdx.x;
    if (tid < 4) acc[tid] = 0.0;
    if (tid == 0) *flag = 0;
    __syncthreads();
    // Safe: done buffer is >= 512 KB in every candidate layout; we scan 4 KB.
    int bad = 0;
    for (int i = tid; i < 1024; i += 256) {
        int v = done_w[i];
        if (!(v == 0 || v == 1 || v == 0x3F800000)) bad = 1;
    }
    if (bad) atomicOr(flag, 1);
}

__global__ __launch_bounds__(256) void policy_k(
    const float* __restrict__ policy,
    const float* __restrict__ behavior,
    const int* __restrict__ actions,
    float* __restrict__ c_arr,
    float* __restrict__ l_arr,
    double* __restrict__ acc)
{
    int r = blockIdx.x * 256 + threadIdx.x;   // row index t*BB+b
    int a = actions[r];
    const float* prow = policy + (size_t)r * AA;
    float ent = 0.f, pi = 1.f, lpi = 0.f;
#pragma unroll
    for (int j = 0; j < 9; ++j) {
        float2 v = *(const float2*)(prow + 2 * j);
        float l0 = __logf(v.x + 1e-10f);
        float l1 = __logf(v.y + 1e-10f);
        ent = fmaf(v.x, l0, ent);
        ent = fmaf(v.y, l1, ent);
        if (2 * j == a)     { pi = v.x; lpi = l0; }
        if (2 * j + 1 == a) { pi = v.y; lpi = l1; }
    }
    float mu = behavior[(size_t)r * AA + a];
    float c = fminf(1.0f, pi / mu);           // clipped rho == cs
    c_arr[r] = c;
    l_arr[r] = lpi;

    // block-reduce entropy partial
    for (int off = 32; off > 0; off >>= 1) ent += __shfl_down(ent, off);
    __shared__ float sred[4];
    int lane = threadIdx.x & 63, wid = threadIdx.x >> 6;
    if (lane == 0) sred[wid] = ent;
    __syncthreads();
    if (threadIdx.x == 0)
        atomicAdd(&acc[0], (double)(sred[0] + sred[1] + sred[2] + sred[3]));
}

__global__ __launch_bounds__(256) void scan_k(
    const float* __restrict__ c_arr,
    const float* __restrict__ l_arr,
    const float* __restrict__ rewards,
    const float* __restrict__ values,
    const float* __restrict__ next_values,
    const void* __restrict__ done,
    const int* __restrict__ flag,
    double* __restrict__ acc)
{
    int b = blockIdx.x * 256 + threadIdx.x;   // column, 0..2047
    const uint8_t* d8 = (const uint8_t*)done;
    const int* d32 = (const int*)done;
    bool bytelay = (*flag != 0);
    float vacc = 0.f, sv = 0.f, sp = 0.f, vnext = 0.f;
#pragma unroll 8
    for (int t = TT - 1; t >= 0; --t) {
        int r = t * BB + b;
        float c = c_arr[r];
        float lpi = l_arr[r];
        float rw = rewards[r];
        float v0 = values[r];
        float nv = next_values[r];
        int dn = bytelay ? (int)d8[r] : d32[r];
        float disc = (dn != 0) ? 0.f : 0.99f;
        float cr = fminf(1.f, fmaxf(-1.f, rw));
        float vt1 = (t == TT - 1) ? nv : vnext;   // values[t+1] or next_values[T-1]
        float base = cr - v0;
        float dlt = c * fmaf(disc, vt1, base);    // deltas[t]
        vacc = fmaf(disc * c, vacc, dlt);         // vs_minus_v_xs[t]
        sv = fmaf(vacc, vacc, sv);                // (vs - values)^2
        float adv = c * fmaf(disc, nv, base);     // pg_adv_vt
        float q = fmaf(disc, v0, base);           // cr + disc*values - values
        sp += adv * lpi * fmaf(disc, vacc, q);    // pg_advantage * log(pi)
        vnext = v0;
    }
    for (int off = 32; off > 0; off >>= 1) {
        sv += __shfl_down(sv, off);
        sp += __shfl_down(sp, off);
    }
    __shared__ float s1[4], s2[4];
    int lane = threadIdx.x & 63, wid = threadIdx.x >> 6;
    if (lane == 0) { s1[wid] = sv; s2[wid] = sp; }
    __syncthreads();
    if (threadIdx.x == 0) {
        atomicAdd(&acc[2], (double)(s1[0] + s1[1] + s1[2] + s1[3]));
        atomicAdd(&acc[1], (double)(s2[0] + s2[1] + s2[2] + s2[3]));
    }
}

__global__ void final_k(const double* __restrict__ acc, float* __restrict__ out) {
    if (threadIdx.x == 0 && blockIdx.x == 0) {
        // total = policy_loss + value_loss + COEF*entropy_loss
        //       = (-S_pol + S_val - 0.01*S_ent) / NTB
        out[0] = (float)((acc[2] - acc[1] - 0.01 * acc[0]) / (double)NTB);
    }
}

extern "C" void kernel_launch(void* const* d_in, const int* in_sizes, int n_in,
                              void* d_out, int out_size, void* d_ws, size_t ws_size,
                              hipStream_t stream) {
    const float* policy      = (const float*)d_in[0];
    const float* behavior    = (const float*)d_in[1];
    const float* rewards     = (const float*)d_in[2];
    const float* values      = (const float*)d_in[3];
    const float* next_values = (const float*)d_in[4];
    const int*   actions     = (const int*)d_in[5];
    const void*  done        = d_in[6];

    double* acc  = (double*)d_ws;
    int*    flag = (int*)((char*)d_ws + 32);
    float*  c_arr = (float*)((char*)d_ws + 64);
    float*  l_arr = c_arr + NTB;

    init_k<<<1, 256, 0, stream>>>((const int*)done, acc, flag);
    policy_k<<<NTB / 256, 256, 0, stream>>>(policy, behavior, actions, c_arr, l_arr, acc);
    scan_k<<<BB / 256, 256, 0, stream>>>(c_arr, l_arr, rewards, values, next_values,
                                         done, flag, acc);
    final_k<<<1, 64, 0, stream>>>(acc, (float*)d_out);
}

// Round 2
// 54.944 us; speedup vs baseline: 1.2978x; 1.2978x over previous
//
#include <hip/hip_runtime.h>
#include <stdint.h>

#define TT 256
#define BB 2048
#define AA 18
#define NTB (TT * BB)
#define NSEG 16
#define SEGLEN 16   // TT / NSEG

// ws layout:
//   [0..31]  4 doubles: acc[0]=S_ent, acc[1]=S_pol, acc[2]=S_val, acc[3]=spare
//   [32..35] int flag: 1 = done is 1-byte elements, 0 = 4-byte elements
//   [64..)   float c_arr[NTB], l_arr[NTB]

__global__ __launch_bounds__(256) void init_k(const int* __restrict__ done_w,
                                              double* __restrict__ acc,
                                              int* __restrict__ flag) {
    int tid = threadIdx.x;
    if (tid < 4) acc[tid] = 0.0;
    if (tid == 0) *flag = 0;
    __syncthreads();
    int bad = 0;
    for (int i = tid; i < 1024; i += 256) {
        int v = done_w[i];
        if (!(v == 0 || v == 1 || v == 0x3F800000)) bad = 1;
    }
    if (bad) atomicOr(flag, 1);
}

__global__ __launch_bounds__(256) void policy_k(
    const float* __restrict__ policy,
    const float* __restrict__ behavior,
    const int* __restrict__ actions,
    float* __restrict__ c_arr,
    float* __restrict__ l_arr,
    double* __restrict__ acc)
{
    int r = blockIdx.x * 256 + threadIdx.x;   // row index t*BB+b
    int a = actions[r];
    const float* prow = policy + (size_t)r * AA;
    float ent = 0.f, pi = 1.f, lpi = 0.f;
#pragma unroll
    for (int j = 0; j < 9; ++j) {
        float2 v = *(const float2*)(prow + 2 * j);
        float l0 = __logf(v.x + 1e-10f);
        float l1 = __logf(v.y + 1e-10f);
        ent = fmaf(v.x, l0, ent);
        ent = fmaf(v.y, l1, ent);
        if (2 * j == a)     { pi = v.x; lpi = l0; }
        if (2 * j + 1 == a) { pi = v.y; lpi = l1; }
    }
    float mu = behavior[(size_t)r * AA + a];
    float c = fminf(1.0f, pi / mu);           // clipped rho == cs
    c_arr[r] = c;
    l_arr[r] = lpi;

    for (int off = 32; off > 0; off >>= 1) ent += __shfl_down(ent, off);
    __shared__ float sred[4];
    int lane = threadIdx.x & 63, wid = threadIdx.x >> 6;
    if (lane == 0) sred[wid] = ent;
    __syncthreads();
    if (threadIdx.x == 0)
        atomicAdd(&acc[0], (double)(sred[0] + sred[1] + sred[2] + sred[3]));
}

// Segmented reverse scan: 1 block per 64 columns; wave w owns timesteps
// [w*SEGLEN, (w+1)*SEGLEN) of its lane's column. Affine-map composition
// (A = prod g, B = vacc with zero carry) + LDS carry fold.
__global__ __launch_bounds__(1024) void scan2_k(
    const float* __restrict__ c_arr,
    const float* __restrict__ l_arr,
    const float* __restrict__ rewards,
    const float* __restrict__ values,
    const float* __restrict__ next_values,
    const void* __restrict__ done,
    const int* __restrict__ flag,
    double* __restrict__ acc)
{
    int lane = threadIdx.x & 63;
    int w = threadIdx.x >> 6;               // segment id 0..15
    int b = blockIdx.x * 64 + lane;         // column
    bool bytelay = (*flag != 0);
    const uint8_t* d8 = (const uint8_t*)done;
    const int* d32 = (const int*)done;
    int t_hi = w * SEGLEN + SEGLEN - 1;

    // ---- pass 1: per-segment affine map (A, Bv) ----
    float A = 1.f, Bv = 0.f;
#pragma unroll 8
    for (int i = 0; i < SEGLEN; ++i) {
        int t = t_hi - i;
        int r = t * BB + b;
        float c = c_arr[r];
        float rw = rewards[r];
        float v0 = values[r];
        int dn = bytelay ? (int)d8[r] : d32[r];
        float disc = dn ? 0.f : 0.99f;
        const float* vt1p = (t == TT - 1) ? (next_values + r) : (values + r + BB);
        float vt1 = *vt1p;
        float cr = fminf(1.f, fmaxf(-1.f, rw));
        float dlt = c * fmaf(disc, vt1, cr - v0);
        float g = disc * c;
        Bv = fmaf(g, Bv, dlt);
        A *= g;
    }
    __shared__ float sA[NSEG][64];
    __shared__ float sB[NSEG][64];
    sA[w][lane] = A;
    sB[w][lane] = Bv;
    __syncthreads();

    // ---- carry fold: carry(w) = vacc[t_hi+1] = fold over segments > w ----
    float carry = 0.f;
#pragma unroll
    for (int s = NSEG - 1; s >= 1; --s) {
        float a2 = sA[s][lane];
        float b2 = sB[s][lane];
        if (s > w) carry = fmaf(a2, carry, b2);
    }

    // ---- pass 2: re-walk with true carry, accumulate the two sums ----
    float vacc = carry, sv = 0.f, sp = 0.f;
#pragma unroll 8
    for (int i = 0; i < SEGLEN; ++i) {
        int t = t_hi - i;
        int r = t * BB + b;
        float c = c_arr[r];
        float lpi = l_arr[r];
        float rw = rewards[r];
        float v0 = values[r];
        float nv = next_values[r];
        int dn = bytelay ? (int)d8[r] : d32[r];
        float disc = dn ? 0.f : 0.99f;
        const float* vt1p = (t == TT - 1) ? (next_values + r) : (values + r + BB);
        float vt1 = *vt1p;
        float cr = fminf(1.f, fmaxf(-1.f, rw));
        float base = cr - v0;
        float dlt = c * fmaf(disc, vt1, base);
        float g = disc * c;
        vacc = fmaf(g, vacc, dlt);              // vs_minus_v_xs[t]
        sv = fmaf(vacc, vacc, sv);              // (vs - values)^2
        float adv = c * fmaf(disc, nv, base);   // pg_adv_vt
        float q = fmaf(disc, v0, base);         // cr + disc*values - values
        sp += adv * lpi * fmaf(disc, vacc, q);  // pg_advantage * log(pi)
    }

    // ---- block reduction ----
    for (int off = 32; off > 0; off >>= 1) {
        sv += __shfl_down(sv, off);
        sp += __shfl_down(sp, off);
    }
    __shared__ float r1[NSEG], r2[NSEG];
    if (lane == 0) { r1[w] = sv; r2[w] = sp; }
    __syncthreads();
    if (threadIdx.x == 0) {
        float tsv = 0.f, tsp = 0.f;
#pragma unroll
        for (int s = 0; s < NSEG; ++s) { tsv += r1[s]; tsp += r2[s]; }
        atomicAdd(&acc[2], (double)tsv);
        atomicAdd(&acc[1], (double)tsp);
    }
}

__global__ void final_k(const double* __restrict__ acc, float* __restrict__ out) {
    if (threadIdx.x == 0 && blockIdx.x == 0) {
        // total = policy_loss + value_loss + COEF*entropy_loss
        //       = (-S_pol + S_val - 0.01*S_ent) / NTB
        out[0] = (float)((acc[2] - acc[1] - 0.01 * acc[0]) / (double)NTB);
    }
}

extern "C" void kernel_launch(void* const* d_in, const int* in_sizes, int n_in,
                              void* d_out, int out_size, void* d_ws, size_t ws_size,
                              hipStream_t stream) {
    const float* policy      = (const float*)d_in[0];
    const float* behavior    = (const float*)d_in[1];
    const float* rewards     = (const float*)d_in[2];
    const float* values      = (const float*)d_in[3];
    const float* next_values = (const float*)d_in[4];
    const int*   actions     = (const int*)d_in[5];
    const void*  done        = d_in[6];

    double* acc  = (double*)d_ws;
    int*    flag = (int*)((char*)d_ws + 32);
    float*  c_arr = (float*)((char*)d_ws + 64);
    float*  l_arr = c_arr + NTB;

    init_k<<<1, 256, 0, stream>>>((const int*)done, acc, flag);
    policy_k<<<NTB / 256, 256, 0, stream>>>(policy, behavior, actions, c_arr, l_arr, acc);
    scan2_k<<<BB / 64, 1024, 0, stream>>>(c_arr, l_arr, rewards, values, next_values,
                                          done, flag, acc);
    final_k<<<1, 64, 0, stream>>>(acc, (float*)d_out);
}

// Round 3
// 40.737 us; speedup vs baseline: 1.7504x; 1.3487x over previous
//
#include <hip/hip_runtime.h>
#include <stdint.h>

#define TT 256
#define BB 2048
#define AA 18
#define NTB (TT * BB)
#define NSEG 32
#define SEGLEN 8     // TT / NSEG
#define NWAVE (NSEG * (BB / 64))   // 1024 waves

// ws layout:
//   [0..31]   4 doubles: acc[0]=S_ent, acc[1]=S_pol, acc[2]=S_val, acc[3]=spare
//   [32..35]  int flag: 1 = done is 1-byte elements, 0 = 4-byte elements
//   [64..)    5 float arrays [NSEG*BB]: A, Bv, sv1, sv2, sp1  (1.25 MB)

#define ARR_ELEMS (NSEG * BB)

__global__ __launch_bounds__(256) void init_k(const int* __restrict__ done_w,
                                              double* __restrict__ acc,
                                              int* __restrict__ flag) {
    int tid = threadIdx.x;
    if (tid < 4) acc[tid] = 0.0;
    if (tid == 0) *flag = 0;
    __syncthreads();
    int bad = 0;
    for (int i = tid; i < 1024; i += 256) {
        int v = done_w[i];
        if (!(v == 0 || v == 1 || v == 0x3F800000)) bad = 1;
    }
    if (bad) atomicOr(flag, 1);
}

// One fused pass: entropy + gather + per-segment scan summaries.
// Wave u (0..1023): segment s = u>>5 (timesteps [s*8, s*8+8)), col-group
// g = u&31 (columns g*64+lane). Within the segment, walk t top-down
// computing the local (carry=0) recurrence and the carry-coupling moments.
__global__ __launch_bounds__(256) void fused_k(
    const float* __restrict__ policy,
    const float* __restrict__ behavior,
    const float* __restrict__ rewards,
    const float* __restrict__ values,
    const float* __restrict__ next_values,
    const int* __restrict__ actions,
    const void* __restrict__ done,
    const int* __restrict__ flag,
    float* __restrict__ wsf,     // 5 arrays of ARR_ELEMS
    double* __restrict__ acc)
{
    int lane = threadIdx.x & 63;
    int w = threadIdx.x >> 6;
    int u = blockIdx.x * 4 + w;
    int s = u >> 5;
    int g = u & 31;
    int b = g * 64 + lane;
    int t_hi = s * SEGLEN + SEGLEN - 1;

    bool bytelay = (*flag != 0);
    const uint8_t* d8 = (const uint8_t*)done;
    const int* d32 = (const int*)done;

    float ent = 0.f;
    float vacc = 0.f, P = 1.f;
    float sv0 = 0.f, sv1 = 0.f, sv2 = 0.f;
    float sp0 = 0.f, sp1 = 0.f;

#pragma unroll 4
    for (int i = 0; i < SEGLEN; ++i) {
        int t = t_hi - i;
        int r = t * BB + b;

        // --- policy row: entropy + select pi, log(pi) ---
        int a = actions[r];
        const float* prow = policy + (size_t)r * AA;
        float pi = 1.f, lpi = 0.f;
#pragma unroll
        for (int j = 0; j < 9; ++j) {
            float2 v = *(const float2*)(prow + 2 * j);
            float l0 = __logf(v.x + 1e-10f);
            float l1 = __logf(v.y + 1e-10f);
            ent = fmaf(v.x, l0, ent);
            ent = fmaf(v.y, l1, ent);
            if (2 * j == a)     { pi = v.x; lpi = l0; }
            if (2 * j + 1 == a) { pi = v.y; lpi = l1; }
        }
        float mu = behavior[(size_t)r * AA + a];
        float c = fminf(1.0f, pi / mu);

        // --- scan inputs ---
        float rw = rewards[r];
        float v0 = values[r];
        float nv = next_values[r];
        int dn = bytelay ? (int)d8[r] : d32[r];
        float disc = dn ? 0.f : 0.99f;
        const float* vt1p = (t == TT - 1) ? (next_values + r) : (values + r + BB);
        float vt1 = *vt1p;

        float cr = fminf(1.f, fmaxf(-1.f, rw));
        float base = cr - v0;
        float dlt = c * fmaf(disc, vt1, base);
        float gg = disc * c;

        vacc = fmaf(gg, vacc, dlt);          // local vs_minus_v (carry = 0)
        P *= gg;                             // P[t] = prod_{tau=t..t_hi} g
        sv0 = fmaf(vacc, vacc, sv0);
        sv1 = fmaf(P, vacc, sv1);
        sv2 = fmaf(P, P, sv2);

        float adv = c * fmaf(disc, nv, base);      // pg_adv_vt
        float q = fmaf(disc, v0, base);            // cr + disc*v0 - v0
        float al = adv * lpi;
        sp0 = fmaf(al, fmaf(disc, vacc, q), sp0);  // carry-independent part
        sp1 = fmaf(al * disc, P, sp1);             // coefficient of carry
    }

    // per-(segment, column) summaries for the fold kernel
    int idx = s * BB + b;
    wsf[0 * ARR_ELEMS + idx] = P;      // A
    wsf[1 * ARR_ELEMS + idx] = vacc;   // Bv (local value at segment bottom)
    wsf[2 * ARR_ELEMS + idx] = sv1;
    wsf[3 * ARR_ELEMS + idx] = sv2;
    wsf[4 * ARR_ELEMS + idx] = sp1;

    // block-reduce carry-independent sums
    for (int off = 32; off > 0; off >>= 1) {
        ent += __shfl_down(ent, off);
        sv0 += __shfl_down(sv0, off);
        sp0 += __shfl_down(sp0, off);
    }
    __shared__ float se[4], sv[4], sp[4];
    if (lane == 0) { se[w] = ent; sv[w] = sv0; sp[w] = sp0; }
    __syncthreads();
    if (threadIdx.x == 0) {
        atomicAdd(&acc[0], (double)(se[0] + se[1] + se[2] + se[3]));
        atomicAdd(&acc[2], (double)(sv[0] + sv[1] + sv[2] + sv[3]));
        atomicAdd(&acc[1], (double)(sp[0] + sp[1] + sp[2] + sp[3]));
    }
}

// Fold segment carries per column; add carry-coupling corrections.
__global__ __launch_bounds__(256) void fold_k(
    const float* __restrict__ wsf,
    double* __restrict__ acc)
{
    int b = blockIdx.x * 256 + threadIdx.x;   // 0..2047
    float C = 0.f;                            // vacc at segment top (vacc[256]=0)
    float svadd = 0.f, spadd = 0.f;
#pragma unroll 8
    for (int s = NSEG - 1; s >= 0; --s) {
        int idx = s * BB + b;
        float A   = wsf[0 * ARR_ELEMS + idx];
        float Bv  = wsf[1 * ARR_ELEMS + idx];
        float sv1 = wsf[2 * ARR_ELEMS + idx];
        float sv2 = wsf[3 * ARR_ELEMS + idx];
        float sp1 = wsf[4 * ARR_ELEMS + idx];
        // sum over segment: (vloc + P*C)^2 = vloc^2 + 2C*P*vloc + C^2*P^2
        svadd = fmaf(2.f * C, sv1, svadd);
        svadd = fmaf(C * C, sv2, svadd);
        spadd = fmaf(C, sp1, spadd);
        C = fmaf(A, C, Bv);                   // carry for segment below
    }
    for (int off = 32; off > 0; off >>= 1) {
        svadd += __shfl_down(svadd, off);
        spadd += __shfl_down(spadd, off);
    }
    __shared__ float s1[4], s2[4];
    int lane = threadIdx.x & 63, w = threadIdx.x >> 6;
    if (lane == 0) { s1[w] = svadd; s2[w] = spadd; }
    __syncthreads();
    if (threadIdx.x == 0) {
        atomicAdd(&acc[2], (double)(s1[0] + s1[1] + s1[2] + s1[3]));
        atomicAdd(&acc[1], (double)(s2[0] + s2[1] + s2[2] + s2[3]));
    }
}

__global__ void final_k(const double* __restrict__ acc, float* __restrict__ out) {
    if (threadIdx.x == 0 && blockIdx.x == 0) {
        // loss = (S_val - S_pol - 0.01*S_ent) / NTB
        out[0] = (float)((acc[2] - acc[1] - 0.01 * acc[0]) / (double)NTB);
    }
}

extern "C" void kernel_launch(void* const* d_in, const int* in_sizes, int n_in,
                              void* d_out, int out_size, void* d_ws, size_t ws_size,
                              hipStream_t stream) {
    const float* policy      = (const float*)d_in[0];
    const float* behavior    = (const float*)d_in[1];
    const float* rewards     = (const float*)d_in[2];
    const float* values      = (const float*)d_in[3];
    const float* next_values = (const float*)d_in[4];
    const int*   actions     = (const int*)d_in[5];
    const void*  done        = d_in[6];

    double* acc  = (double*)d_ws;
    int*    flag = (int*)((char*)d_ws + 32);
    float*  wsf  = (float*)((char*)d_ws + 64);

    init_k<<<1, 256, 0, stream>>>((const int*)done, acc, flag);
    fused_k<<<NWAVE / 4, 256, 0, stream>>>(policy, behavior, rewards, values,
                                           next_values, actions, done, flag,
                                           wsf, acc);
    fold_k<<<BB / 256, 256, 0, stream>>>(wsf, acc);
    final_k<<<1, 64, 0, stream>>>(acc, (float*)d_out);
}